// Round 4
// baseline (762.069 us; speedup 1.0000x reference)
//
#include <hip/hip_runtime.h>

// Problem constants
#define BB    16
#define NN    729
#define DD    1152
#define HH_   16
#define HDIM  72
#define NPAD  736
#define HDPAD 96
#define MTOK  (BB*NN)   // 11664
#define ESTR  768       // E row stride in bf16 elements (bank-aligned, XOR-swizzled)

typedef __attribute__((ext_vector_type(8))) short bf16x8;
typedef __attribute__((ext_vector_type(4))) float f32x4;

__device__ __forceinline__ unsigned short f2bf(float f) {
  unsigned u = __float_as_uint(f);
  u += 0x7fffu + ((u >> 16) & 1u);
  return (unsigned short)(u >> 16);
}
__device__ __forceinline__ float bf2f(unsigned short s) {
  return __uint_as_float(((unsigned)s) << 16);
}

__device__ __forceinline__ void gload_lds16(const void* g, void* l) {
  __builtin_amdgcn_global_load_lds(
      (const __attribute__((address_space(1))) void*)(unsigned long long)g,
      (__attribute__((address_space(3))) void*)(unsigned)(unsigned long long)l,
      16, 0, 0);
}

// ---------------- cast kernels ----------------
__global__ __launch_bounds__(256) void cast_x_kernel(const float* __restrict__ in,
                                                     unsigned short* __restrict__ out, int n4) {
  int i = blockIdx.x * 256 + threadIdx.x;
  for (; i < n4; i += gridDim.x * 256) {
    float4 v = ((const float4*)in)[i];
    uint2 o;
    o.x = (unsigned)f2bf(v.x) | ((unsigned)f2bf(v.y) << 16);
    o.y = (unsigned)f2bf(v.z) | ((unsigned)f2bf(v.w) << 16);
    ((uint2*)out)[i] = o;
  }
}

__global__ __launch_bounds__(256) void cast_w_kernel(const float* __restrict__ wq,
                                                     const float* __restrict__ wk,
                                                     const float* __restrict__ wv,
                                                     const float* __restrict__ wo,
                                                     unsigned short* __restrict__ out) {
  const int per = DD * DD / 4;
  int i = blockIdx.x * 256 + threadIdx.x;
  for (; i < 4 * per; i += gridDim.x * 256) {
    const int which = i / per, off = i - which * per;
    const float* src = which == 0 ? wq : which == 1 ? wk : which == 2 ? wv : wo;
    float4 v = ((const float4*)src)[off];
    uint2 o;
    o.x = (unsigned)f2bf(v.x) | ((unsigned)f2bf(v.y) << 16);
    o.y = (unsigned)f2bf(v.z) | ((unsigned)f2bf(v.w) << 16);
    ((uint2*)out)[i] = o;
  }
}

// ---------------- log(size) table: (16, 736) fp32 ----------------
__global__ __launch_bounds__(256) void ls_kernel(const float* __restrict__ tsize,
                                                 float* __restrict__ LSg) {
  const int idx = blockIdx.x * 256 + threadIdx.x;
  if (idx < BB * NPAD) {
    const int b = idx / NPAD, k = idx - b * NPAD;
    LSg[idx] = (k < NN) ? __logf(tsize[b * NN + k]) : -1e30f;
  }
}

// ---------------- pad-zero: Q/K hd-pads + K tail rows ----------------
__global__ __launch_bounds__(256) void pad_kernel(unsigned short* __restrict__ Qb,
                                                  unsigned short* __restrict__ Kb) {
  const int bh = blockIdx.x, t = threadIdx.x;
  unsigned short* q = Qb + (size_t)bh * NPAD * HDPAD;
  unsigned short* k = Kb + (size_t)bh * NPAD * HDPAD;
  const uint4 z = {0, 0, 0, 0};
  for (int n = t; n < NPAD; n += 256) {
    uint4* qa = (uint4*)(q + n * HDPAD + 72);
    qa[0] = z; qa[1] = z; qa[2] = z;
    uint4* ka = (uint4*)(k + n * HDPAD + 72);
    ka[0] = z; ka[1] = z; ka[2] = z;
  }
  for (int i = t; i < 7 * 36; i += 256) {  // K tail rows 729..735, hd 0..72
    const int r = i / 36, c = i - (i / 36) * 36;
    ((unsigned*)(k + (size_t)(729 + r) * HDPAD))[c] = 0;
  }
}

// ---------------- V transpose: (b,n,1152 row-major) -> (bh, hd, n) padded ----------------
__global__ __launch_bounds__(256) void vt_kernel(const unsigned short* __restrict__ Vtmp,
                                                 unsigned short* __restrict__ Vt) {
  __shared__ unsigned short tile[128][73];
  const int bh = blockIdx.x, nt = blockIdx.y;
  const int b = bh >> 4, hh = bh & 15;
  const int n0 = nt * 128;
  const int t = threadIdx.x;
  const int ncnt = (NPAD - n0) < 128 ? (NPAD - n0) : 128;
  for (int i = t; i < ncnt * 36; i += 256) {
    const int n = i / 36, c = i - (i / 36) * 36;
    unsigned u = 0;
    if (n0 + n < NN)
      u = *(const unsigned*)(Vtmp + ((size_t)(b * NN + n0 + n)) * DD + hh * HDIM + c * 2);
    tile[n][c * 2] = (unsigned short)(u & 0xffffu);
    tile[n][c * 2 + 1] = (unsigned short)(u >> 16);
  }
  __syncthreads();
  const int nq = ncnt >> 2;
  for (int i = t; i < 72 * nq; i += 256) {
    const int hd = i / nq, nc = (i - hd * nq) * 4;
    uint2 o;
    o.x = (unsigned)tile[nc][hd] | ((unsigned)tile[nc + 1][hd] << 16);
    o.y = (unsigned)tile[nc + 2][hd] | ((unsigned)tile[nc + 3][hd] << 16);
    *(uint2*)(Vt + ((size_t)bh * HDPAD + hd) * NPAD + n0 + nc) = o;
  }
}

// ---------------- GEMM: C = A(bf16 Mx1152) * Bw(rows=features x 1152)^T ----------------
// MODE 0: QKV -> Q/K padded (bh,n,hd); V row-major tokensx1152 into Vtmp
// MODE 1: out-proj -> fp32 out (+bias)
template <int MODE>
__global__ __launch_bounds__(256) void gemm_kernel(
    const unsigned short* __restrict__ A,
    const unsigned short* __restrict__ Bw,
    const float* __restrict__ b0, const float* __restrict__ b1, const float* __restrict__ b2,
    unsigned short* __restrict__ O0, unsigned short* __restrict__ O1, unsigned short* __restrict__ O2,
    float* __restrict__ Of, int NBX) {
  __shared__ __align__(16) unsigned short As[128 * 64];
  __shared__ __align__(16) unsigned short Bs[128 * 64];
  const int tid = threadIdx.x;
  const int w = tid >> 6, l = tid & 63;
  const int lr = l & 15, lh = l >> 4;
  // bijective XCD-chunked swizzle
  const int nblk = gridDim.x;
  const int x = blockIdx.x & 7, o = blockIdx.x >> 3;
  const int qq = nblk >> 3, rr = nblk & 7;
  const int wg = (x < rr ? x * (qq + 1) : rr * (qq + 1) + (x - rr) * qq) + o;
  const int m0 = (wg % NBX) * 128;
  const int n0 = (wg / NBX) * 128;
  const int wr = (w >> 1) * 64, wc = (w & 1) * 64;

  const f32x4 fz = {0.f, 0.f, 0.f, 0.f};
  f32x4 acc[4][4];
#pragma unroll
  for (int i = 0; i < 4; ++i)
#pragma unroll
    for (int j = 0; j < 4; ++j) acc[i][j] = fz;

  for (int kt = 0; kt < 18; ++kt) {
    const int k0 = kt * 64;
#pragma unroll
    for (int c = 0; c < 4; ++c) {
      const int off = (c * 256 + tid) * 16;
      const int row = off >> 7, kb = off & 127;
      int grow = m0 + row;
      if (grow > MTOK - 1) grow = MTOK - 1;
      gload_lds16((const char*)A + (size_t)grow * 2304 + k0 * 2 + kb, (char*)As + off);
    }
#pragma unroll
    for (int c = 0; c < 4; ++c) {
      const int off = (c * 256 + tid) * 16;
      const int row = off >> 7, kb = off & 127;
      gload_lds16((const char*)Bw + (size_t)(n0 + row) * 2304 + k0 * 2 + kb, (char*)Bs + off);
    }
    __syncthreads();
#pragma unroll
    for (int kk = 0; kk < 64; kk += 32) {
      bf16x8 af[4], bf[4];
#pragma unroll
      for (int mi = 0; mi < 4; ++mi)
        af[mi] = *(const bf16x8*)((const char*)As + ((wr + mi * 16 + lr) * 64 + kk + lh * 8) * 2);
#pragma unroll
      for (int ni = 0; ni < 4; ++ni)
        bf[ni] = *(const bf16x8*)((const char*)Bs + ((wc + ni * 16 + lr) * 64 + kk + lh * 8) * 2);
#pragma unroll
      for (int mi = 0; mi < 4; ++mi)
#pragma unroll
        for (int ni = 0; ni < 4; ++ni)
          acc[mi][ni] = __builtin_amdgcn_mfma_f32_16x16x32_bf16(af[mi], bf[ni], acc[mi][ni], 0, 0, 0);
    }
    __syncthreads();
  }

#pragma unroll
  for (int mi = 0; mi < 4; ++mi)
#pragma unroll
    for (int ni = 0; ni < 4; ++ni) {
      const int col = n0 + wc + ni * 16 + lr;
#pragma unroll
      for (int j = 0; j < 4; ++j) {
        const int row = m0 + wr + mi * 16 + lh * 4 + j;
        if (row < MTOK) {
          float v = acc[mi][ni][j];
          if (MODE == 0) {
            const int which = col / DD;
            const int ec = col - which * DD;
            const float* bias = which == 0 ? b0 : (which == 1 ? b1 : b2);
            v += bias[ec];
            const unsigned short bv = f2bf(v);
            if (which == 2) {
              O2[(size_t)row * DD + ec] = bv;  // V row-major (coalesced)
            } else {
              const int h = ec / HDIM, hd = ec - h * HDIM;
              const int bb = row / NN, n = row - bb * NN;
              if (which == 0)
                O0[(((size_t)bb * HH_ + h) * NPAD + n) * HDPAD + hd] = bv;
              else
                O1[(((size_t)bb * HH_ + h) * NPAD + n) * HDPAD + hd] = bv;
            }
          } else {
            Of[(size_t)row * DD + col] = v + b0[col];
          }
        }
      }
    }
}

// ---------------- attention v4: 512 thr/WG per (b*h, 32-query tile) ----------------
// phase1: all 8 waves compute E=exp(QK^T*scale+LS) -> swizzled LDS.
// then wave-split: waves 0-5 PV MFMA; waves 6-7 row-sums + 545MB attn write (overlapped).
__global__ __launch_bounds__(512, 6) void attn_kernel(
    const unsigned short* __restrict__ Qb,
    const unsigned short* __restrict__ Kb,
    const unsigned short* __restrict__ Vt,
    const float* __restrict__ LSg,
    float* __restrict__ attn_out,
    unsigned short* __restrict__ Ab) {
  __shared__ __align__(16) char smem[49280];
  unsigned short* Elds = (unsigned short*)smem;
  float* INV = (float*)(smem + 49152);
  float* red = (float*)smem;

  const int tid = threadIdx.x, w = tid >> 6, l = tid & 63;
  const int lr = l & 15, lh = l >> 4;

  // bijective XCD-chunked swizzle: 5888 WGs = 8 x 736
  const int id = blockIdx.x;
  const int nid = (id & 7) * 736 + (id >> 3);
  const int bh = nid / 23, qt = nid - bh * 23;
  const int b = bh >> 4, hh = bh & 15;
  const int q0 = qt * 32;
  const int qv = NN - q0;

  const float scale = 0.11785113019775793f;  // 72^-0.5
  const size_t kvbase = (size_t)bh * NPAD * HDPAD;
  const unsigned short* qp = Qb + kvbase + (size_t)q0 * HDPAD;

  // Q fragments hoisted (loop-invariant)
  bf16x8 aq[2][3];
#pragma unroll
  for (int mi = 0; mi < 2; ++mi)
#pragma unroll
    for (int ks = 0; ks < 3; ++ks)
      aq[mi][ks] = *(const bf16x8*)(qp + (size_t)(mi * 16 + lr) * HDPAD + ks * 32 + lh * 8);

  // ---- phase 1 ----
  for (int kt = w; kt < 23; kt += 8) {
    const int k0 = kt * 32;
    const f32x4 fz = {0.f, 0.f, 0.f, 0.f};
    f32x4 acc[2][2];
    acc[0][0] = fz; acc[0][1] = fz; acc[1][0] = fz; acc[1][1] = fz;
    const unsigned short* kp = Kb + kvbase + (size_t)k0 * HDPAD;
#pragma unroll
    for (int ks = 0; ks < 3; ++ks) {
      const bf16x8 bk0 = *(const bf16x8*)(kp + (size_t)lr * HDPAD + ks * 32 + lh * 8);
      const bf16x8 bk1 = *(const bf16x8*)(kp + (size_t)(16 + lr) * HDPAD + ks * 32 + lh * 8);
#pragma unroll
      for (int mi = 0; mi < 2; ++mi) {
        acc[mi][0] = __builtin_amdgcn_mfma_f32_16x16x32_bf16(aq[mi][ks], bk0, acc[mi][0], 0, 0, 0);
        acc[mi][1] = __builtin_amdgcn_mfma_f32_16x16x32_bf16(aq[mi][ks], bk1, acc[mi][1], 0, 0, 0);
      }
    }
#pragma unroll
    for (int ni = 0; ni < 2; ++ni) {
      const int col = k0 + ni * 16 + lr;
      const float lsv = LSg[b * NPAD + col];
#pragma unroll
      for (int mi = 0; mi < 2; ++mi)
#pragma unroll
        for (int j = 0; j < 4; ++j) {
          const int row = mi * 16 + lh * 4 + j;
          const int swcol = col ^ ((row & 7) << 3);
          Elds[row * ESTR + swcol] = f2bf(__expf(acc[mi][ni][j] * scale + lsv));
        }
    }
  }
  __syncthreads();

  const int m = w & 1, kq = w >> 1;
  const f32x4 fz = {0.f, 0.f, 0.f, 0.f};
  f32x4 acc2[5];
#pragma unroll
  for (int ni = 0; ni < 5; ++ni) acc2[ni] = fz;

  if (w >= 6) {
    // ---- waves 6,7: row sums + normalized attn write ----
    const int t2 = tid - 384;  // 0..127
    const int r = t2 >> 2, sub = t2 & 3;
    const int sw = (r & 7) << 3;
    const unsigned short* er = Elds + r * ESTR;
    float s = 0.f;
#pragma unroll
    for (int i = 0; i < 46; ++i) {
      const int col = sub * 184 + i * 4;
      const uint2 ev = *(const uint2*)(er + (col ^ sw));
      s += bf2f(ev.x & 0xffffu) + bf2f(ev.x >> 16) + bf2f(ev.y & 0xffffu) + bf2f(ev.y >> 16);
    }
    s += __shfl_xor(s, 1);
    s += __shfl_xor(s, 2);
    const float inv = 1.f / s;
    if (sub == 0) INV[r] = inv;
    if (r < qv) {
      float* ao = attn_out + ((size_t)bh * NN + (q0 + r)) * NN;
#pragma unroll
      for (int i = 0; i < 46; ++i) {
        const int col = sub * 184 + i * 4;
        if (col + 4 <= NN) {
          const uint2 ev = *(const uint2*)(er + (col ^ sw));
          float4 o;
          o.x = bf2f(ev.x & 0xffffu) * inv;
          o.y = bf2f(ev.x >> 16) * inv;
          o.z = bf2f(ev.y & 0xffffu) * inv;
          o.w = bf2f(ev.y >> 16) * inv;
          *(float4*)(ao + col) = o;
        } else if (col < NN) {
          for (int c = col; c < NN; ++c) ao[c] = bf2f(er[c ^ sw]) * inv;
        }
      }
    }
  } else {
    // ---- waves 0-5: PV. wave = (m half, kq third). V^T B-frags direct from global. ----
    const int kt0 = kq * 8, kt1 = (kq == 2) ? 23 : kt0 + 8;
    const unsigned short* vp = Vt + (size_t)bh * HDPAD * NPAD;
    const int row = m * 16 + lr;
    const int sw = (row & 7) << 3;
    for (int kt = kt0; kt < kt1; ++kt) {
      const int k0 = kt * 32;
      const bf16x8 ap = *(const bf16x8*)(Elds + row * ESTR + ((k0 + lh * 8) ^ sw));
#pragma unroll
      for (int ni = 0; ni < 5; ++ni) {
        const bf16x8 bv = *(const bf16x8*)(vp + (size_t)(ni * 16 + lr) * NPAD + k0 + lh * 8);
        acc2[ni] = __builtin_amdgcn_mfma_f32_16x16x32_bf16(ap, bv, acc2[ni], 0, 0, 0);
      }
    }
  }
  __syncthreads();  // all Elds reads done

  if (w < 6 && kq > 0) {
    float* rd = red + ((kq - 1) * 2 + m) * 1344;  // 16 x 84 fp32
#pragma unroll
    for (int ni = 0; ni < 5; ++ni)
#pragma unroll
      for (int j = 0; j < 4; ++j)
        rd[(lh * 4 + j) * 84 + ni * 16 + lr] = acc2[ni][j];
  }
  __syncthreads();
  if (w < 2) {
#pragma unroll
    for (int ni = 0; ni < 5; ++ni) {
      const int d = ni * 16 + lr;
      if (d < HDIM) {
#pragma unroll
        for (int j = 0; j < 4; ++j) {
          const int rrow = m * 16 + lh * 4 + j;
          const int q = q0 + rrow;
          if (q < NN) {
            const int ro = (lh * 4 + j) * 84 + ni * 16 + lr;
            const float s2 = acc2[ni][j] + red[m * 1344 + ro] + red[(2 + m) * 1344 + ro];
            Ab[((size_t)b * NN + q) * DD + hh * HDIM + d] = f2bf(s2 * INV[rrow]);
          }
        }
      }
    }
  }
}

// ---------------- metric = mean over heads of K ----------------
__global__ __launch_bounds__(256) void metric_kernel(const unsigned short* __restrict__ Kb,
                                                     float* __restrict__ out) {
  const int total = BB * NN * HDIM;
  int idx = blockIdx.x * 256 + threadIdx.x;
  for (; idx < total; idx += gridDim.x * 256) {
    const int b = idx / (NN * HDIM);
    const int rem = idx - b * NN * HDIM;
    const int n = rem / HDIM, d = rem - n * HDIM;
    const unsigned short* kp = Kb + (((size_t)b * HH_) * NPAD + n) * HDPAD + d;
    float s = 0.f;
#pragma unroll
    for (int h = 0; h < HH_; ++h) s += bf2f(kp[(size_t)h * NPAD * HDPAD]);
    out[idx] = s * 0.0625f;
  }
}

extern "C" void kernel_launch(void* const* d_in, const int* in_sizes, int n_in,
                              void* d_out, int out_size, void* d_ws, size_t ws_size,
                              hipStream_t stream) {
  const float* X = (const float*)d_in[0];
  const float* sz = (const float*)d_in[1];
  const float* Wq = (const float*)d_in[2];
  const float* bq = (const float*)d_in[3];
  const float* Wk = (const float*)d_in[4];
  const float* bk = (const float*)d_in[5];
  const float* Wv = (const float*)d_in[6];
  const float* bv = (const float*)d_in[7];
  const float* Wo = (const float*)d_in[8];
  const float* bo = (const float*)d_in[9];

  char* ws = (char*)d_ws;
  unsigned short* Xb = (unsigned short*)ws;                  // 11664x1152 bf16
  unsigned short* Wb = (unsigned short*)(ws + 26873856);     // 4x(1152x1152) bf16 (q,k,v,o)
  unsigned short* Qb = (unsigned short*)(ws + 37490688);     // (16,16,736,96) bf16
  unsigned short* Kb = (unsigned short*)(ws + 73666560);     // (16,16,736,96) bf16
  unsigned short* Vt = (unsigned short*)(ws + 109842432);    // (16,16,96,736) bf16 transposed
  unsigned short* Ab = (unsigned short*)(ws + 146018304);    // 11664x1152 bf16
  unsigned short* Vtmp = Ab;                                 // V row-major, dead before attn writes Ab
  float* LSg = (float*)ws;  // (16,736) fp32 log-size; aliases Xb, written AFTER gemm<0>

  float* out = (float*)d_out;
  float* attn = out + 13436928;
  float* metric = out + 149485824;

  cast_x_kernel<<<2048, 256, 0, stream>>>(X, Xb, 3359232);
  cast_w_kernel<<<2048, 256, 0, stream>>>(Wq, Wk, Wv, Wo, Wb);

  gemm_kernel<0><<<2484, 256, 0, stream>>>(Xb, Wb, bq, bk, bv, Qb, Kb, Vtmp, nullptr, 92);

  ls_kernel<<<46, 256, 0, stream>>>(sz, LSg);            // Xb dead now
  vt_kernel<<<dim3(256, 6), 256, 0, stream>>>(Vtmp, Vt); // V -> padded V^T (zeroes n-pads)
  pad_kernel<<<256, 256, 0, stream>>>(Qb, Kb);           // Q/K hd-pads + K tail rows

  attn_kernel<<<5888, 512, 0, stream>>>(Qb, Kb, Vt, LSg, attn, Ab);

  gemm_kernel<1><<<828, 256, 0, stream>>>(Ab, Wb + (size_t)3456 * 1152, bo, nullptr, nullptr,
                                          nullptr, nullptr, nullptr, out, 92);

  metric_kernel<<<2048, 256, 0, stream>>>(Kb, metric);
}

// Round 5
// 700.677 us; speedup vs baseline: 1.0876x; 1.0876x over previous
//
#include <hip/hip_runtime.h>

// Problem constants
#define BB    16
#define NN    729
#define DD    1152
#define HH_   16
#define HDIM  72
#define NPAD  736
#define HDPAD 96
#define MTOK  (BB*NN)   // 11664
#define ESTR  768       // E row stride in bf16 elements (bank-aligned, XOR-swizzled)

typedef __attribute__((ext_vector_type(8))) short bf16x8;
typedef __attribute__((ext_vector_type(4))) float f32x4;

__device__ __forceinline__ unsigned short f2bf(float f) {
  unsigned u = __float_as_uint(f);
  u += 0x7fffu + ((u >> 16) & 1u);
  return (unsigned short)(u >> 16);
}
__device__ __forceinline__ float bf2f(unsigned short s) {
  return __uint_as_float(((unsigned)s) << 16);
}

__device__ __forceinline__ void gload_lds16(const void* g, void* l) {
  __builtin_amdgcn_global_load_lds(
      (const __attribute__((address_space(1))) void*)(unsigned long long)g,
      (__attribute__((address_space(3))) void*)(unsigned)(unsigned long long)l,
      16, 0, 0);
}

// ---------------- cast kernels ----------------
__global__ __launch_bounds__(256) void cast_x_kernel(const float* __restrict__ in,
                                                     unsigned short* __restrict__ out, int n4) {
  int i = blockIdx.x * 256 + threadIdx.x;
  for (; i < n4; i += gridDim.x * 256) {
    float4 v = ((const float4*)in)[i];
    uint2 o;
    o.x = (unsigned)f2bf(v.x) | ((unsigned)f2bf(v.y) << 16);
    o.y = (unsigned)f2bf(v.z) | ((unsigned)f2bf(v.w) << 16);
    ((uint2*)out)[i] = o;
  }
}

__global__ __launch_bounds__(256) void cast_w_kernel(const float* __restrict__ wq,
                                                     const float* __restrict__ wk,
                                                     const float* __restrict__ wv,
                                                     const float* __restrict__ wo,
                                                     unsigned short* __restrict__ out) {
  const int per = DD * DD / 4;
  int i = blockIdx.x * 256 + threadIdx.x;
  for (; i < 4 * per; i += gridDim.x * 256) {
    const int which = i / per, off = i - which * per;
    const float* src = which == 0 ? wq : which == 1 ? wk : which == 2 ? wv : wo;
    float4 v = ((const float4*)src)[off];
    uint2 o;
    o.x = (unsigned)f2bf(v.x) | ((unsigned)f2bf(v.y) << 16);
    o.y = (unsigned)f2bf(v.z) | ((unsigned)f2bf(v.w) << 16);
    ((uint2*)out)[i] = o;
  }
}

// ---------------- log(size) table: (16, 736) fp32 ----------------
__global__ __launch_bounds__(256) void ls_kernel(const float* __restrict__ tsize,
                                                 float* __restrict__ LSg) {
  const int idx = blockIdx.x * 256 + threadIdx.x;
  if (idx < BB * NPAD) {
    const int b = idx / NPAD, k = idx - b * NPAD;
    LSg[idx] = (k < NN) ? __logf(tsize[b * NN + k]) : -1e30f;
  }
}

// ---------------- pad-zero: Q/K hd-pads + K tail rows ----------------
__global__ __launch_bounds__(256) void pad_kernel(unsigned short* __restrict__ Qb,
                                                  unsigned short* __restrict__ Kb) {
  const int bh = blockIdx.x, t = threadIdx.x;
  unsigned short* q = Qb + (size_t)bh * NPAD * HDPAD;
  unsigned short* k = Kb + (size_t)bh * NPAD * HDPAD;
  const uint4 z = {0, 0, 0, 0};
  for (int n = t; n < NPAD; n += 256) {
    uint4* qa = (uint4*)(q + n * HDPAD + 72);
    qa[0] = z; qa[1] = z; qa[2] = z;
    uint4* ka = (uint4*)(k + n * HDPAD + 72);
    ka[0] = z; ka[1] = z; ka[2] = z;
  }
  for (int i = t; i < 7 * 36; i += 256) {  // K tail rows 729..735, hd 0..72
    const int r = i / 36, c = i - (i / 36) * 36;
    ((unsigned*)(k + (size_t)(729 + r) * HDPAD))[c] = 0;
  }
}

// ---------------- V transpose: (b,n,1152 row-major) -> (bh, hd, n) padded ----------------
__global__ __launch_bounds__(256) void vt_kernel(const unsigned short* __restrict__ Vtmp,
                                                 unsigned short* __restrict__ Vt) {
  __shared__ unsigned short tile[128][73];
  const int bh = blockIdx.x, nt = blockIdx.y;
  const int b = bh >> 4, hh = bh & 15;
  const int n0 = nt * 128;
  const int t = threadIdx.x;
  const int ncnt = (NPAD - n0) < 128 ? (NPAD - n0) : 128;
  for (int i = t; i < ncnt * 36; i += 256) {
    const int n = i / 36, c = i - (i / 36) * 36;
    unsigned u = 0;
    if (n0 + n < NN)
      u = *(const unsigned*)(Vtmp + ((size_t)(b * NN + n0 + n)) * DD + hh * HDIM + c * 2);
    tile[n][c * 2] = (unsigned short)(u & 0xffffu);
    tile[n][c * 2 + 1] = (unsigned short)(u >> 16);
  }
  __syncthreads();
  const int nq = ncnt >> 2;
  for (int i = t; i < 72 * nq; i += 256) {
    const int hd = i / nq, nc = (i - hd * nq) * 4;
    uint2 o;
    o.x = (unsigned)tile[nc][hd] | ((unsigned)tile[nc + 1][hd] << 16);
    o.y = (unsigned)tile[nc + 2][hd] | ((unsigned)tile[nc + 3][hd] << 16);
    *(uint2*)(Vt + ((size_t)bh * HDPAD + hd) * NPAD + n0 + nc) = o;
  }
}

// ---------------- GEMM: C = A(bf16 Mx1152) * Bw(rows=features x 1152)^T ----------------
// MODE 0: QKV -> Q/K padded (bh,n,hd); V row-major tokensx1152 into Vtmp
// MODE 1: out-proj -> fp32 out (+bias)
template <int MODE>
__global__ __launch_bounds__(256) void gemm_kernel(
    const unsigned short* __restrict__ A,
    const unsigned short* __restrict__ Bw,
    const float* __restrict__ b0, const float* __restrict__ b1, const float* __restrict__ b2,
    unsigned short* __restrict__ O0, unsigned short* __restrict__ O1, unsigned short* __restrict__ O2,
    float* __restrict__ Of, int NBX) {
  __shared__ __align__(16) unsigned short As[128 * 64];
  __shared__ __align__(16) unsigned short Bs[128 * 64];
  const int tid = threadIdx.x;
  const int w = tid >> 6, l = tid & 63;
  const int lr = l & 15, lh = l >> 4;
  // bijective XCD-chunked swizzle
  const int nblk = gridDim.x;
  const int x = blockIdx.x & 7, o = blockIdx.x >> 3;
  const int qq = nblk >> 3, rr = nblk & 7;
  const int wg = (x < rr ? x * (qq + 1) : rr * (qq + 1) + (x - rr) * qq) + o;
  const int m0 = (wg % NBX) * 128;
  const int n0 = (wg / NBX) * 128;
  const int wr = (w >> 1) * 64, wc = (w & 1) * 64;

  const f32x4 fz = {0.f, 0.f, 0.f, 0.f};
  f32x4 acc[4][4];
#pragma unroll
  for (int i = 0; i < 4; ++i)
#pragma unroll
    for (int j = 0; j < 4; ++j) acc[i][j] = fz;

  for (int kt = 0; kt < 18; ++kt) {
    const int k0 = kt * 64;
#pragma unroll
    for (int c = 0; c < 4; ++c) {
      const int off = (c * 256 + tid) * 16;
      const int row = off >> 7, kb = off & 127;
      int grow = m0 + row;
      if (grow > MTOK - 1) grow = MTOK - 1;
      gload_lds16((const char*)A + (size_t)grow * 2304 + k0 * 2 + kb, (char*)As + off);
    }
#pragma unroll
    for (int c = 0; c < 4; ++c) {
      const int off = (c * 256 + tid) * 16;
      const int row = off >> 7, kb = off & 127;
      gload_lds16((const char*)Bw + (size_t)(n0 + row) * 2304 + k0 * 2 + kb, (char*)Bs + off);
    }
    __syncthreads();
#pragma unroll
    for (int kk = 0; kk < 64; kk += 32) {
      bf16x8 af[4], bf[4];
#pragma unroll
      for (int mi = 0; mi < 4; ++mi)
        af[mi] = *(const bf16x8*)((const char*)As + ((wr + mi * 16 + lr) * 64 + kk + lh * 8) * 2);
#pragma unroll
      for (int ni = 0; ni < 4; ++ni)
        bf[ni] = *(const bf16x8*)((const char*)Bs + ((wc + ni * 16 + lr) * 64 + kk + lh * 8) * 2);
#pragma unroll
      for (int mi = 0; mi < 4; ++mi)
#pragma unroll
        for (int ni = 0; ni < 4; ++ni)
          acc[mi][ni] = __builtin_amdgcn_mfma_f32_16x16x32_bf16(af[mi], bf[ni], acc[mi][ni], 0, 0, 0);
    }
    __syncthreads();
  }

#pragma unroll
  for (int mi = 0; mi < 4; ++mi)
#pragma unroll
    for (int ni = 0; ni < 4; ++ni) {
      const int col = n0 + wc + ni * 16 + lr;
#pragma unroll
      for (int j = 0; j < 4; ++j) {
        const int row = m0 + wr + mi * 16 + lh * 4 + j;
        if (row < MTOK) {
          float v = acc[mi][ni][j];
          if (MODE == 0) {
            const int which = col / DD;
            const int ec = col - which * DD;
            const float* bias = which == 0 ? b0 : (which == 1 ? b1 : b2);
            v += bias[ec];
            const unsigned short bv = f2bf(v);
            if (which == 2) {
              O2[(size_t)row * DD + ec] = bv;  // V row-major (coalesced)
            } else {
              const int h = ec / HDIM, hd = ec - h * HDIM;
              const int bb = row / NN, n = row - bb * NN;
              if (which == 0)
                O0[(((size_t)bb * HH_ + h) * NPAD + n) * HDPAD + hd] = bv;
              else
                O1[(((size_t)bb * HH_ + h) * NPAD + n) * HDPAD + hd] = bv;
            }
          } else {
            Of[(size_t)row * DD + col] = v + b0[col];
          }
        }
      }
    }
}

// ---------------- attention v5: 512 thr/WG per (b*h, 32-query tile) ----------------
// phase1: all 8 waves compute E=exp(QK^T*scale+LS) -> swizzled LDS.
// wave-split: waves 0-5 PV MFMA; waves 6-7 row-sums + attn write, one row per
// iteration with all 64 lanes -> every store instruction is 1KB contiguous.
__global__ __launch_bounds__(512, 6) void attn_kernel(
    const unsigned short* __restrict__ Qb,
    const unsigned short* __restrict__ Kb,
    const unsigned short* __restrict__ Vt,
    const float* __restrict__ LSg,
    float* __restrict__ attn_out,
    unsigned short* __restrict__ Ab) {
  __shared__ __align__(16) char smem[49280];
  unsigned short* Elds = (unsigned short*)smem;
  float* INV = (float*)(smem + 49152);
  float* red = (float*)smem;

  const int tid = threadIdx.x, w = tid >> 6, l = tid & 63;
  const int lr = l & 15, lh = l >> 4;

  // bijective XCD-chunked swizzle: 5888 WGs = 8 x 736
  const int id = blockIdx.x;
  const int nid = (id & 7) * 736 + (id >> 3);
  const int bh = nid / 23, qt = nid - bh * 23;
  const int b = bh >> 4, hh = bh & 15;
  const int q0 = qt * 32;
  const int qv = NN - q0;

  const float scale = 0.11785113019775793f;  // 72^-0.5
  const size_t kvbase = (size_t)bh * NPAD * HDPAD;
  const unsigned short* qp = Qb + kvbase + (size_t)q0 * HDPAD;

  // Q fragments hoisted (loop-invariant)
  bf16x8 aq[2][3];
#pragma unroll
  for (int mi = 0; mi < 2; ++mi)
#pragma unroll
    for (int ks = 0; ks < 3; ++ks)
      aq[mi][ks] = *(const bf16x8*)(qp + (size_t)(mi * 16 + lr) * HDPAD + ks * 32 + lh * 8);

  // ---- phase 1 ----
  for (int kt = w; kt < 23; kt += 8) {
    const int k0 = kt * 32;
    const f32x4 fz = {0.f, 0.f, 0.f, 0.f};
    f32x4 acc[2][2];
    acc[0][0] = fz; acc[0][1] = fz; acc[1][0] = fz; acc[1][1] = fz;
    const unsigned short* kp = Kb + kvbase + (size_t)k0 * HDPAD;
#pragma unroll
    for (int ks = 0; ks < 3; ++ks) {
      const bf16x8 bk0 = *(const bf16x8*)(kp + (size_t)lr * HDPAD + ks * 32 + lh * 8);
      const bf16x8 bk1 = *(const bf16x8*)(kp + (size_t)(16 + lr) * HDPAD + ks * 32 + lh * 8);
#pragma unroll
      for (int mi = 0; mi < 2; ++mi) {
        acc[mi][0] = __builtin_amdgcn_mfma_f32_16x16x32_bf16(aq[mi][ks], bk0, acc[mi][0], 0, 0, 0);
        acc[mi][1] = __builtin_amdgcn_mfma_f32_16x16x32_bf16(aq[mi][ks], bk1, acc[mi][1], 0, 0, 0);
      }
    }
#pragma unroll
    for (int ni = 0; ni < 2; ++ni) {
      const int col = k0 + ni * 16 + lr;
      const float lsv = LSg[b * NPAD + col];
#pragma unroll
      for (int mi = 0; mi < 2; ++mi)
#pragma unroll
        for (int j = 0; j < 4; ++j) {
          const int row = mi * 16 + lh * 4 + j;
          const int swcol = col ^ ((row & 7) << 3);
          Elds[row * ESTR + swcol] = f2bf(__expf(acc[mi][ni][j] * scale + lsv));
        }
    }
  }
  __syncthreads();

  const int m = w & 1, kq = w >> 1;
  const f32x4 fz = {0.f, 0.f, 0.f, 0.f};
  f32x4 acc2[5];
#pragma unroll
  for (int ni = 0; ni < 5; ++ni) acc2[ni] = fz;

  if (w >= 6) {
    // ---- waves 6,7: per-row sums + fully-coalesced attn write (1KB/instr) ----
    const int rbase = (w - 6) * 16;
    float* aobase = attn_out + ((size_t)bh * NN + q0) * NN;
    for (int rr2 = 0; rr2 < 16; ++rr2) {
      const int r = rbase + rr2;
      const int sw = (r & 7) << 3;
      const unsigned short* er = Elds + r * ESTR;
      float4 vals[3];
      float s = 0.f;
#pragma unroll
      for (int i = 0; i < 3; ++i) {
        const int col = i * 256 + l * 4;
        if (col < NPAD) {
          const uint2 ev = *(const uint2*)(er + (col ^ sw));
          float4 o;
          o.x = bf2f(ev.x & 0xffffu);
          o.y = bf2f(ev.x >> 16);
          o.z = bf2f(ev.y & 0xffffu);
          o.w = bf2f(ev.y >> 16);
          vals[i] = o;
          s += o.x + o.y + o.z + o.w;
        } else {
          const float4 z4 = {0.f, 0.f, 0.f, 0.f};
          vals[i] = z4;
        }
      }
#pragma unroll
      for (int o2 = 1; o2 < 64; o2 <<= 1) s += __shfl_xor(s, o2);
      const float inv = 1.f / s;
      if (l == 0) INV[r] = inv;
      if (r < qv) {
        float* ao = aobase + (size_t)r * NN;
#pragma unroll
        for (int i = 0; i < 3; ++i) {
          const int col = i * 256 + l * 4;
          if (col + 4 <= NN) {
            float4 o = vals[i];
            o.x *= inv; o.y *= inv; o.z *= inv; o.w *= inv;
            *(float4*)(ao + col) = o;
          } else if (col < NN) {
            ao[col] = vals[i].x * inv;  // col == 728
          }
        }
      }
    }
  } else {
    // ---- waves 0-5: PV. wave = (m half, kq third). V^T B-frags direct from global. ----
    const int kt0 = kq * 8, kt1 = (kq == 2) ? 23 : kt0 + 8;
    const unsigned short* vp = Vt + (size_t)bh * HDPAD * NPAD;
    const int row = m * 16 + lr;
    const int sw = (row & 7) << 3;
    for (int kt = kt0; kt < kt1; ++kt) {
      const int k0 = kt * 32;
      const bf16x8 ap = *(const bf16x8*)(Elds + row * ESTR + ((k0 + lh * 8) ^ sw));
#pragma unroll
      for (int ni = 0; ni < 5; ++ni) {
        const bf16x8 bv = *(const bf16x8*)(vp + (size_t)(ni * 16 + lr) * NPAD + k0 + lh * 8);
        acc2[ni] = __builtin_amdgcn_mfma_f32_16x16x32_bf16(ap, bv, acc2[ni], 0, 0, 0);
      }
    }
  }
  __syncthreads();  // all Elds reads done

  if (w < 6 && kq > 0) {
    float* rd = red + ((kq - 1) * 2 + m) * 1344;  // 16 x 84 fp32
#pragma unroll
    for (int ni = 0; ni < 5; ++ni)
#pragma unroll
      for (int j = 0; j < 4; ++j)
        rd[(lh * 4 + j) * 84 + ni * 16 + lr] = acc2[ni][j];
  }
  __syncthreads();
  if (w < 2) {
#pragma unroll
    for (int ni = 0; ni < 5; ++ni) {
      const int d = ni * 16 + lr;
      if (d < HDIM) {
#pragma unroll
        for (int j = 0; j < 4; ++j) {
          const int rrow = m * 16 + lh * 4 + j;
          const int q = q0 + rrow;
          if (q < NN) {
            const int ro = (lh * 4 + j) * 84 + ni * 16 + lr;
            const float s2 = acc2[ni][j] + red[m * 1344 + ro] + red[(2 + m) * 1344 + ro];
            Ab[((size_t)b * NN + q) * DD + hh * HDIM + d] = f2bf(s2 * INV[rrow]);
          }
        }
      }
    }
  }
}

// ---------------- metric = mean over heads of K ----------------
__global__ __launch_bounds__(256) void metric_kernel(const unsigned short* __restrict__ Kb,
                                                     float* __restrict__ out) {
  const int total = BB * NN * HDIM;
  int idx = blockIdx.x * 256 + threadIdx.x;
  for (; idx < total; idx += gridDim.x * 256) {
    const int b = idx / (NN * HDIM);
    const int rem = idx - b * NN * HDIM;
    const int n = rem / HDIM, d = rem - n * HDIM;
    const unsigned short* kp = Kb + (((size_t)b * HH_) * NPAD + n) * HDPAD + d;
    float s = 0.f;
#pragma unroll
    for (int h = 0; h < HH_; ++h) s += bf2f(kp[(size_t)h * NPAD * HDPAD]);
    out[idx] = s * 0.0625f;
  }
}

extern "C" void kernel_launch(void* const* d_in, const int* in_sizes, int n_in,
                              void* d_out, int out_size, void* d_ws, size_t ws_size,
                              hipStream_t stream) {
  const float* X = (const float*)d_in[0];
  const float* sz = (const float*)d_in[1];
  const float* Wq = (const float*)d_in[2];
  const float* bq = (const float*)d_in[3];
  const float* Wk = (const float*)d_in[4];
  const float* bk = (const float*)d_in[5];
  const float* Wv = (const float*)d_in[6];
  const float* bv = (const float*)d_in[7];
  const float* Wo = (const float*)d_in[8];
  const float* bo = (const float*)d_in[9];

  char* ws = (char*)d_ws;
  unsigned short* Xb = (unsigned short*)ws;                  // 11664x1152 bf16
  unsigned short* Wb = (unsigned short*)(ws + 26873856);     // 4x(1152x1152) bf16 (q,k,v,o)
  unsigned short* Qb = (unsigned short*)(ws + 37490688);     // (16,16,736,96) bf16
  unsigned short* Kb = (unsigned short*)(ws + 73666560);     // (16,16,736,96) bf16
  unsigned short* Vt = (unsigned short*)(ws + 109842432);    // (16,16,96,736) bf16 transposed
  unsigned short* Ab = (unsigned short*)(ws + 146018304);    // 11664x1152 bf16
  unsigned short* Vtmp = Ab;                                 // V row-major, dead before attn writes Ab
  float* LSg = (float*)ws;  // (16,736) fp32 log-size; aliases Xb, written AFTER gemm<0>

  float* out = (float*)d_out;
  float* attn = out + 13436928;
  float* metric = out + 149485824;

  cast_x_kernel<<<2048, 256, 0, stream>>>(X, Xb, 3359232);
  cast_w_kernel<<<2048, 256, 0, stream>>>(Wq, Wk, Wv, Wo, Wb);

  gemm_kernel<0><<<2484, 256, 0, stream>>>(Xb, Wb, bq, bk, bv, Qb, Kb, Vtmp, nullptr, 92);

  ls_kernel<<<46, 256, 0, stream>>>(sz, LSg);            // Xb dead now
  vt_kernel<<<dim3(256, 6), 256, 0, stream>>>(Vtmp, Vt); // V -> padded V^T (zeroes n-pads)
  pad_kernel<<<256, 256, 0, stream>>>(Qb, Kb);           // Q/K hd-pads + K tail rows

  attn_kernel<<<5888, 512, 0, stream>>>(Qb, Kb, Vt, LSg, attn, Ab);

  gemm_kernel<1><<<828, 256, 0, stream>>>(Ab, Wb + (size_t)3456 * 1152, bo, nullptr, nullptr,
                                          nullptr, nullptr, nullptr, out, 92);

  metric_kernel<<<2048, 256, 0, stream>>>(Kb, metric);
}

// Round 6
// 629.720 us; speedup vs baseline: 1.2102x; 1.1127x over previous
//
#include <hip/hip_runtime.h>

// Problem constants
#define BB    16
#define NN    729
#define DD    1152
#define HH_   16
#define HDIM  72
#define NPAD  736
#define HDPAD 96
#define MTOK  (BB*NN)   // 11664
#define ESTR  768       // attn E row stride (bf16, swizzled)

typedef __attribute__((ext_vector_type(8))) short bf16x8;
typedef __attribute__((ext_vector_type(4))) float f32x4;

__device__ __forceinline__ unsigned short f2bf(float f) {
  unsigned u = __float_as_uint(f);
  u += 0x7fffu + ((u >> 16) & 1u);
  return (unsigned short)(u >> 16);
}
__device__ __forceinline__ float bf2f(unsigned short s) {
  return __uint_as_float(((unsigned)s) << 16);
}

__device__ __forceinline__ void gload_lds16(const void* g, void* l) {
  __builtin_amdgcn_global_load_lds(
      (const __attribute__((address_space(1))) void*)(unsigned long long)g,
      (__attribute__((address_space(3))) void*)(unsigned)(unsigned long long)l,
      16, 0, 0);
}

// ---------------- cast kernels ----------------
__global__ __launch_bounds__(256) void cast_x_kernel(const float* __restrict__ in,
                                                     unsigned short* __restrict__ out, int n4) {
  int i = blockIdx.x * 256 + threadIdx.x;
  for (; i < n4; i += gridDim.x * 256) {
    float4 v = ((const float4*)in)[i];
    uint2 o;
    o.x = (unsigned)f2bf(v.x) | ((unsigned)f2bf(v.y) << 16);
    o.y = (unsigned)f2bf(v.z) | ((unsigned)f2bf(v.w) << 16);
    ((uint2*)out)[i] = o;
  }
}

__global__ __launch_bounds__(256) void cast_w_kernel(const float* __restrict__ wq,
                                                     const float* __restrict__ wk,
                                                     const float* __restrict__ wv,
                                                     const float* __restrict__ wo,
                                                     unsigned short* __restrict__ out) {
  const int per = DD * DD / 4;
  int i = blockIdx.x * 256 + threadIdx.x;
  for (; i < 4 * per; i += gridDim.x * 256) {
    const int which = i / per, off = i - which * per;
    const float* src = which == 0 ? wq : which == 1 ? wk : which == 2 ? wv : wo;
    float4 v = ((const float4*)src)[off];
    uint2 o;
    o.x = (unsigned)f2bf(v.x) | ((unsigned)f2bf(v.y) << 16);
    o.y = (unsigned)f2bf(v.z) | ((unsigned)f2bf(v.w) << 16);
    ((uint2*)out)[i] = o;
  }
}

// ---------------- log(size) table ----------------
__global__ __launch_bounds__(256) void ls_kernel(const float* __restrict__ tsize,
                                                 float* __restrict__ LSg) {
  const int idx = blockIdx.x * 256 + threadIdx.x;
  if (idx < BB * NPAD) {
    const int b = idx / NPAD, k = idx - b * NPAD;
    LSg[idx] = (k < NN) ? __logf(tsize[b * NN + k]) : -1e30f;
  }
}

// ---------------- pad-zero: Q/K hd-pads + K tail rows ----------------
__global__ __launch_bounds__(256) void pad_kernel(unsigned short* __restrict__ Qb,
                                                  unsigned short* __restrict__ Kb) {
  const int bh = blockIdx.x, t = threadIdx.x;
  unsigned short* q = Qb + (size_t)bh * NPAD * HDPAD;
  unsigned short* k = Kb + (size_t)bh * NPAD * HDPAD;
  const uint4 z = {0, 0, 0, 0};
  for (int n = t; n < NPAD; n += 256) {
    uint4* qa = (uint4*)(q + n * HDPAD + 72);
    qa[0] = z; qa[1] = z; qa[2] = z;
    uint4* ka = (uint4*)(k + n * HDPAD + 72);
    ka[0] = z; ka[1] = z; ka[2] = z;
  }
  for (int i = t; i < 7 * 36; i += 256) {
    const int r = i / 36, c = i - (i / 36) * 36;
    ((unsigned*)(k + (size_t)(729 + r) * HDPAD))[c] = 0;
  }
}

// ---------------- V transpose ----------------
__global__ __launch_bounds__(256) void vt_kernel(const unsigned short* __restrict__ Vtmp,
                                                 unsigned short* __restrict__ Vt) {
  __shared__ unsigned short tile[128][73];
  const int bh = blockIdx.x, nt = blockIdx.y;
  const int b = bh >> 4, hh = bh & 15;
  const int n0 = nt * 128;
  const int t = threadIdx.x;
  const int ncnt = (NPAD - n0) < 128 ? (NPAD - n0) : 128;
  for (int i = t; i < ncnt * 36; i += 256) {
    const int n = i / 36, c = i - (i / 36) * 36;
    unsigned u = 0;
    if (n0 + n < NN)
      u = *(const unsigned*)(Vtmp + ((size_t)(b * NN + n0 + n)) * DD + hh * HDIM + c * 2);
    tile[n][c * 2] = (unsigned short)(u & 0xffffu);
    tile[n][c * 2 + 1] = (unsigned short)(u >> 16);
  }
  __syncthreads();
  const int nq = ncnt >> 2;
  for (int i = t; i < 72 * nq; i += 256) {
    const int hd = i / nq, nc = (i - hd * nq) * 4;
    uint2 o;
    o.x = (unsigned)tile[nc][hd] | ((unsigned)tile[nc + 1][hd] << 16);
    o.y = (unsigned)tile[nc + 2][hd] | ((unsigned)tile[nc + 3][hd] << 16);
    *(uint2*)(Vt + ((size_t)bh * HDPAD + hd) * NPAD + n0 + nc) = o;
  }
}

// ---------------- 8-phase 256x256x64 GEMM ----------------
// C = A(Mx1152) * Bw(rows=features x 1152)^T.  512 thr, 8 waves (2Mx4N),
// 128KB dbuf LDS, swizzled staging (pre-swizzled global source), counted vmcnt.
#define PH_MID() \
  __builtin_amdgcn_s_barrier(); \
  asm volatile("s_waitcnt lgkmcnt(0)" ::: "memory"); \
  __builtin_amdgcn_sched_barrier(0); \
  __builtin_amdgcn_s_setprio(1)
#define PH_END() \
  __builtin_amdgcn_s_setprio(0); \
  __builtin_amdgcn_s_barrier()
#define QUAD(MB, NB) \
  _Pragma("unroll") for (int mr = 0; mr < 4; ++mr) \
  _Pragma("unroll") for (int nr = 0; nr < 2; ++nr) \
  _Pragma("unroll") for (int s = 0; s < 2; ++s) \
    acc[(MB) + mr][(NB) + nr] = __builtin_amdgcn_mfma_f32_16x16x32_bf16( \
        a[mr][s], b[(NB) + nr][s], acc[(MB) + mr][(NB) + nr], 0, 0, 0)

template <int MODE>
__global__ __launch_bounds__(512, 2) void gemm8_kernel(
    const unsigned short* __restrict__ A,
    const unsigned short* __restrict__ Bw,
    const float* __restrict__ bi0, const float* __restrict__ bi1, const float* __restrict__ bi2,
    unsigned short* __restrict__ O0, unsigned short* __restrict__ O1, unsigned short* __restrict__ O2,
    float* __restrict__ Of, int NBX, int nlim) {
  __shared__ __align__(16) char smem[131072];
  const int tid = threadIdx.x, w = tid >> 6, l = tid & 63;
  const int lr = l & 15, lh = l >> 4;
  const int wm = w >> 2, wn = w & 3;
  const int xr = (lr & 7) << 4;

  // bijective XCD-chunked swizzle
  const int nblk = gridDim.x;
  const int xc = blockIdx.x & 7, oo = blockIdx.x >> 3;
  const int qq = nblk >> 3, rr = nblk & 7;
  const int wg = (xc < rr ? xc * (qq + 1) : rr * (qq + 1) + (xc - rr) * qq) + oo;
  const int m0 = (wg % NBX) * 256;
  const int n0 = (wg / NBX) * 256;

  f32x4 acc[8][4];
  const f32x4 fz = {0.f, 0.f, 0.f, 0.f};
#pragma unroll
  for (int i = 0; i < 8; ++i)
#pragma unroll
    for (int j = 0; j < 4; ++j) acc[i][j] = fz;

  // stage one 16KB half-tile (128 rows x 64 k) of K-step kt into LDS base.
  // LDS dest linear; global source pre-swizzled with involution g = b ^ ((b>>7&7)<<4).
  auto stage = [&](const unsigned short* mat, int rlim, int row0, int kt, char* base) {
#pragma unroll
    for (int c = 0; c < 2; ++c) {
      const int beta = w * 1024 + c * 8192 + l * 16;
      const int g = beta ^ (((beta >> 7) & 7) << 4);
      int grow = row0 + (g >> 7);
      if (grow > rlim) grow = rlim;
      gload_lds16((const char*)mat + (size_t)grow * 2304 + kt * 128 + (g & 127), base + beta);
    }
  };
  bf16x8 a[4][2], b[4][2];
  auto lda = [&](char* Ab, int mh) {
#pragma unroll
    for (int mr = 0; mr < 4; ++mr)
#pragma unroll
      for (int s = 0; s < 2; ++s) {
        const int x = (wm * 128 + mh * 64 + mr * 16 + lr) * 128 + s * 64 + lh * 16;
        a[mr][s] = *(const bf16x8*)(Ab + (x ^ xr));
      }
  };
  auto ldb = [&](char* Bb, int nh) {
#pragma unroll
    for (int nr = 0; nr < 2; ++nr)
#pragma unroll
      for (int s = 0; s < 2; ++s) {
        const int x = (wn * 64 + nh * 32 + nr * 16 + lr) * 128 + s * 64 + lh * 16;
        b[nh * 2 + nr][s] = *(const bf16x8*)(Bb + (x ^ xr));
      }
  };

  // prologue: A(0), B(0), A(1) -> vmcnt(4) leaves A(1) pair in flight
  stage(A, MTOK - 1, m0, 0, smem);
  stage(A, MTOK - 1, m0 + 128, 0, smem + 16384);
  stage(Bw, nlim, n0, 0, smem + 32768);
  stage(Bw, nlim, n0 + 128, 0, smem + 49152);
  stage(A, MTOK - 1, m0, 1, smem + 65536);
  stage(A, MTOK - 1, m0 + 128, 1, smem + 81920);
  asm volatile("s_waitcnt vmcnt(4)" ::: "memory");
  __builtin_amdgcn_s_barrier();

#pragma unroll 2
  for (int k = 0; k < 18; ++k) {
    char* Ac = smem + (k & 1) * 65536;
    char* Bc = Ac + 32768;
    char* An = smem + ((k + 1) & 1) * 65536;
    char* Bn = An + 32768;
    const int kb = (k + 1 < 18) ? k + 1 : 17;
    const int ka = (k + 2 < 18) ? k + 2 : 17;
    // q0: read A mh0 + B nh0; stage B0(k+1)
    lda(Ac, 0);
    ldb(Bc, 0);
    stage(Bw, nlim, n0, kb, Bn);
    PH_MID();
    QUAD(0, 0);
    PH_END();
    // q1: read B nh1; stage B1(k+1)
    ldb(Bc, 1);
    stage(Bw, nlim, n0 + 128, kb, Bn + 16384);
    PH_MID();
    QUAD(0, 2);
    PH_END();
    // q2: read A mh1
    lda(Ac, 1);
    PH_MID();
    QUAD(4, 2);
    PH_END();
    // q3: stage A0,A1(k+2) into current buffer (A region fully consumed at q2)
    stage(A, MTOK - 1, m0, ka, Ac);
    stage(A, MTOK - 1, m0 + 128, ka, Ac + 16384);
    PH_MID();
    QUAD(4, 0);
    __builtin_amdgcn_s_setprio(0);
    asm volatile("s_waitcnt vmcnt(4)" ::: "memory");  // tile k+1 landed; 2 HTs in flight
    __builtin_amdgcn_s_barrier();
  }

  // epilogue
#pragma unroll
  for (int mi = 0; mi < 8; ++mi)
#pragma unroll
    for (int ni = 0; ni < 4; ++ni) {
      const int col = n0 + wn * 64 + ni * 16 + lr;
#pragma unroll
      for (int j = 0; j < 4; ++j) {
        const int row = m0 + wm * 128 + mi * 16 + lh * 4 + j;
        if (row < MTOK) {
          float v = acc[mi][ni][j];
          if (MODE == 0) {
            if (col < 3 * DD) {
              const int which = col / DD;
              const int ec = col - which * DD;
              const float* bias = which == 0 ? bi0 : (which == 1 ? bi1 : bi2);
              v += bias[ec];
              const unsigned short bv = f2bf(v);
              if (which == 2) {
                O2[(size_t)row * DD + ec] = bv;  // V row-major
              } else {
                const int h = ec / HDIM, hd = ec - h * HDIM;
                const int bb = row / NN, n = row - bb * NN;
                if (which == 0)
                  O0[(((size_t)bb * HH_ + h) * NPAD + n) * HDPAD + hd] = bv;
                else
                  O1[(((size_t)bb * HH_ + h) * NPAD + n) * HDPAD + hd] = bv;
              }
            }
          } else {
            if (col < DD) Of[(size_t)row * DD + col] = v + bi0[col];
          }
        }
      }
    }
}

// ---------------- attention (R3-verified structure + Q-hoist) ----------------
__global__ __launch_bounds__(512, 6) void attn_kernel(
    const unsigned short* __restrict__ Qb,
    const unsigned short* __restrict__ Kb,
    const unsigned short* __restrict__ Vt,
    const float* __restrict__ LSg,
    float* __restrict__ attn_out,
    unsigned short* __restrict__ Ab) {
  __shared__ __align__(16) char smem[49280];
  unsigned short* Elds = (unsigned short*)smem;
  float* INV = (float*)(smem + 49152);
  float* red = (float*)smem;

  const int tid = threadIdx.x, w = tid >> 6, l = tid & 63;
  const int lr = l & 15, lh = l >> 4;

  const int id = blockIdx.x;
  const int nid = (id & 7) * 736 + (id >> 3);
  const int bh = nid / 23, qt = nid - bh * 23;
  const int b = bh >> 4, hh = bh & 15;
  const int q0 = qt * 32;

  const float scale = 0.11785113019775793f;  // 72^-0.5
  const size_t kvbase = (size_t)bh * NPAD * HDPAD;
  const unsigned short* qp = Qb + kvbase + (size_t)q0 * HDPAD;

  bf16x8 aq[2][3];
#pragma unroll
  for (int mi = 0; mi < 2; ++mi)
#pragma unroll
    for (int ks = 0; ks < 3; ++ks)
      aq[mi][ks] = *(const bf16x8*)(qp + (size_t)(mi * 16 + lr) * HDPAD + ks * 32 + lh * 8);

  // ---- phase 1: E = exp(QK^T*scale + LS) -> swizzled LDS ----
  for (int kt = w; kt < 23; kt += 8) {
    const int k0 = kt * 32;
    const f32x4 fz = {0.f, 0.f, 0.f, 0.f};
    f32x4 acc[2][2];
    acc[0][0] = fz; acc[0][1] = fz; acc[1][0] = fz; acc[1][1] = fz;
    const unsigned short* kp = Kb + kvbase + (size_t)k0 * HDPAD;
#pragma unroll
    for (int ks = 0; ks < 3; ++ks) {
      const bf16x8 bk0 = *(const bf16x8*)(kp + (size_t)lr * HDPAD + ks * 32 + lh * 8);
      const bf16x8 bk1 = *(const bf16x8*)(kp + (size_t)(16 + lr) * HDPAD + ks * 32 + lh * 8);
#pragma unroll
      for (int mi = 0; mi < 2; ++mi) {
        acc[mi][0] = __builtin_amdgcn_mfma_f32_16x16x32_bf16(aq[mi][ks], bk0, acc[mi][0], 0, 0, 0);
        acc[mi][1] = __builtin_amdgcn_mfma_f32_16x16x32_bf16(aq[mi][ks], bk1, acc[mi][1], 0, 0, 0);
      }
    }
#pragma unroll
    for (int ni = 0; ni < 2; ++ni) {
      const int col = k0 + ni * 16 + lr;
      const float lsv = LSg[b * NPAD + col];
#pragma unroll
      for (int mi = 0; mi < 2; ++mi)
#pragma unroll
        for (int j = 0; j < 4; ++j) {
          const int row = mi * 16 + lh * 4 + j;
          const int swcol = col ^ ((row & 7) << 3);
          Elds[row * ESTR + swcol] = f2bf(__expf(acc[mi][ni][j] * scale + lsv));
        }
    }
  }
  __syncthreads();

  // ---- phase 2: row sums -> INV (16 threads per row) ----
  {
    const int r = tid >> 4, sub = tid & 15;
    const unsigned short* er = Elds + r * ESTR;
    const int sw = (r & 7) << 3;
    float s = 0.f;
#pragma unroll
    for (int i = 0; i < 12; ++i) {
      const int col = i * 64 + sub * 4;
      if (col < NPAD) {
        const uint2 ev = *(const uint2*)(er + (col ^ sw));
        s += bf2f(ev.x & 0xffffu) + bf2f(ev.x >> 16) + bf2f(ev.y & 0xffffu) + bf2f(ev.y >> 16);
      }
    }
#pragma unroll
    for (int o = 1; o < 16; o <<= 1) s += __shfl_xor(s, o);
    if (sub == 0) INV[r] = 1.f / s;
  }
  __syncthreads();

  // ---- phase 3: normalized P -> global attn ----
  const int qv = NN - q0;
  {
    const int r = tid >> 4, sub = tid & 15;
    if (r < qv) {
      const float inv = INV[r];
      float* ao = attn_out + ((size_t)bh * NN + (q0 + r)) * NN;
      const unsigned short* er = Elds + r * ESTR;
      const int sw = (r & 7) << 3;
#pragma unroll
      for (int i = 0; i < 12; ++i) {
        const int col = i * 64 + sub * 4;
        if (col + 4 <= NN) {
          const uint2 ev = *(const uint2*)(er + (col ^ sw));
          float4 o;
          o.x = bf2f(ev.x & 0xffffu) * inv;
          o.y = bf2f(ev.x >> 16) * inv;
          o.z = bf2f(ev.y & 0xffffu) * inv;
          o.w = bf2f(ev.y >> 16) * inv;
          *(float4*)(ao + col) = o;
        } else if (col < NN) {
          for (int c = col; c < NN; ++c) ao[c] = bf2f(er[c ^ sw]) * inv;
        }
      }
    }
  }

  // ---- phase 4: PV ----
  const int m = w & 1, kq = w >> 1;
  const f32x4 fz = {0.f, 0.f, 0.f, 0.f};
  f32x4 acc2[5];
#pragma unroll
  for (int ni = 0; ni < 5; ++ni) acc2[ni] = fz;
  {
    const int kt0 = kq * 6, kt1 = (kq == 3) ? 23 : kt0 + 6;
    const unsigned short* vp = Vt + (size_t)bh * HDPAD * NPAD;
    const int row = m * 16 + lr;
    const int sw = (row & 7) << 3;
    for (int kt = kt0; kt < kt1; ++kt) {
      const int k0 = kt * 32;
      const bf16x8 ap = *(const bf16x8*)(Elds + row * ESTR + ((k0 + lh * 8) ^ sw));
#pragma unroll
      for (int ni = 0; ni < 5; ++ni) {
        const bf16x8 bv = *(const bf16x8*)(vp + (size_t)(ni * 16 + lr) * NPAD + k0 + lh * 8);
        acc2[ni] = __builtin_amdgcn_mfma_f32_16x16x32_bf16(ap, bv, acc2[ni], 0, 0, 0);
      }
    }
  }
  __syncthreads();

  if (kq > 0) {
    float* rd = red + ((kq - 1) * 2 + m) * 1344;
#pragma unroll
    for (int ni = 0; ni < 5; ++ni)
#pragma unroll
      for (int j = 0; j < 4; ++j)
        rd[(lh * 4 + j) * 84 + ni * 16 + lr] = acc2[ni][j];
  }
  __syncthreads();
  if (kq == 0) {
#pragma unroll
    for (int ni = 0; ni < 5; ++ni) {
      const int d = ni * 16 + lr;
      if (d < HDIM) {
#pragma unroll
        for (int j = 0; j < 4; ++j) {
          const int rrow = m * 16 + lh * 4 + j;
          const int q = q0 + rrow;
          if (q < NN) {
            const int ro = (lh * 4 + j) * 84 + ni * 16 + lr;
            const float s2 = acc2[ni][j] + red[m * 1344 + ro] + red[(2 + m) * 1344 + ro] +
                             red[(4 + m) * 1344 + ro];
            Ab[((size_t)b * NN + q) * DD + hh * HDIM + d] = f2bf(s2 * INV[rrow]);
          }
        }
      }
    }
  }
}

// ---------------- metric ----------------
__global__ __launch_bounds__(256) void metric_kernel(const unsigned short* __restrict__ Kb,
                                                     float* __restrict__ out) {
  const int total = BB * NN * HDIM;
  int idx = blockIdx.x * 256 + threadIdx.x;
  for (; idx < total; idx += gridDim.x * 256) {
    const int b = idx / (NN * HDIM);
    const int rem = idx - b * NN * HDIM;
    const int n = rem / HDIM, d = rem - n * HDIM;
    const unsigned short* kp = Kb + (((size_t)b * HH_) * NPAD + n) * HDPAD + d;
    float s = 0.f;
#pragma unroll
    for (int h = 0; h < HH_; ++h) s += bf2f(kp[(size_t)h * NPAD * HDPAD]);
    out[idx] = s * 0.0625f;
  }
}

extern "C" void kernel_launch(void* const* d_in, const int* in_sizes, int n_in,
                              void* d_out, int out_size, void* d_ws, size_t ws_size,
                              hipStream_t stream) {
  const float* X = (const float*)d_in[0];
  const float* sz = (const float*)d_in[1];
  const float* Wq = (const float*)d_in[2];
  const float* bq = (const float*)d_in[3];
  const float* Wk = (const float*)d_in[4];
  const float* bk = (const float*)d_in[5];
  const float* Wv = (const float*)d_in[6];
  const float* bv = (const float*)d_in[7];
  const float* Wo = (const float*)d_in[8];
  const float* bo = (const float*)d_in[9];

  char* ws = (char*)d_ws;
  unsigned short* Xb = (unsigned short*)ws;                  // 11664x1152 bf16
  unsigned short* Wb = (unsigned short*)(ws + 26873856);     // 4x(1152x1152) bf16
  unsigned short* Qb = (unsigned short*)(ws + 37490688);     // (16,16,736,96)
  unsigned short* Kb = (unsigned short*)(ws + 73666560);     // (16,16,736,96)
  unsigned short* Vt = (unsigned short*)(ws + 109842432);    // (16,16,96,736)
  unsigned short* Ab = (unsigned short*)(ws + 146018304);    // 11664x1152 bf16
  unsigned short* Vtmp = Ab;                                 // V row-major (dead before attn)
  float* LSg = (float*)ws;                                   // aliases Xb (dead after gemm0)

  float* out = (float*)d_out;
  float* attn = out + 13436928;
  float* metric = out + 149485824;

  cast_x_kernel<<<2048, 256, 0, stream>>>(X, Xb, 3359232);
  cast_w_kernel<<<2048, 256, 0, stream>>>(Wq, Wk, Wv, Wo, Wb);

  gemm8_kernel<0><<<644, 512, 0, stream>>>(Xb, Wb, bq, bk, bv, Qb, Kb, Vtmp, nullptr, 46, 3455);

  ls_kernel<<<46, 256, 0, stream>>>(sz, LSg);
  vt_kernel<<<dim3(256, 6), 256, 0, stream>>>(Vtmp, Vt);
  pad_kernel<<<256, 256, 0, stream>>>(Qb, Kb);

  attn_kernel<<<5888, 512, 0, stream>>>(Qb, Kb, Vt, LSg, attn, Ab);

  gemm8_kernel<1><<<230, 512, 0, stream>>>(Ab, Wb + (size_t)3456 * 1152, bo, nullptr, nullptr,
                                           nullptr, nullptr, nullptr, out, 46, 1151);

  metric_kernel<<<2048, 256, 0, stream>>>(Kb, metric);
}